// Round 7
// baseline (305.231 us; speedup 1.0000x reference)
//
#include <hip/hip_runtime.h>

// Problem constants (static per reference): x shape (B, C, H, W) fp32
#define B   64
#define C   2048
#define H   24
#define W   12
#define S   (H * W)        // 288 spatial positions per (b, c)
#define S4  (S / 4)        // 72 float4 per channel slice
#define W4  (W / 4)        // 3 float4 per row
#define NCH 32             // channel chunks
#define CCH (C / NCH)      // 64 channels per chunk
#define RH  8              // round(0.33 * 24)

// Native clang vector type — required by __builtin_nontemporal_store
// (HIP's float4 is a struct wrapper it rejects). Lowers to dwordx4 ops.
typedef float f4 __attribute__((ext_vector_type(4)));

// ---------------------------------------------------------------------------
// Round-7: COPY-THEN-PATCH with NONTEMPORAL stores everywhere.
// Round-6 lesson: temporal copy stores parked 151 MB of dirty out-lines in
// L2/MALL; the writebacks drained during the harness poison fills, dropping
// them from 84% to 68% of peak (+42 us) — more than the structure saved.
// NT stores write through immediately inside our own kernel's time and keep
// the cache clean for the fills (this was the hidden role of NT in rounds
// 0-5 too).
// Structure rationale (unchanged): the mask depends on the full reduction
// but the COPY doesn't -> pass 1 copies x verbatim while accumulating
// energy (x read from HBM exactly once, no second 151 MB stream + 82 MB
// HBM re-fetch), pass 2 zero-patches only the 8 dropped rows per sample
// (50 MB of partial-line NT writes, ~1.5-2x RMW cost, still ~2x cheaper
// than the re-stream it replaces).
// ---------------------------------------------------------------------------

// ---------------------------------------------------------------------------
// Kernel 1: fused energy + verbatim copy. Block (chunk, b), 288 threads.
// Thread t, iteration k accesses float4 index t + 288k within the chunk's
// 4608-float4 span -> the block walks contiguous 4.6 KB spans, perfectly
// coalesced both directions. Thread t's 4 spatial positions are fixed
// (spatial f4 = t%72, channel = t/72 + 4k) -> register accumulate.
// Loads batched 8-deep (compiler alone pipelines only ~4-deep).
// ---------------------------------------------------------------------------
__global__ __launch_bounds__(288) void k_energy_copy(const float* __restrict__ x,
                                                     float* __restrict__ out,
                                                     float* __restrict__ part) {
    const int chunk = blockIdx.x;   // 0..NCH-1
    const int b     = blockIdx.y;   // 0..B-1
    const int t     = threadIdx.x;  // 0..287
    const int f     = t % S4;
    const int g     = t / S4;

    const size_t base4 = (size_t)(b * C + chunk * CCH) * S4;
    const f4* __restrict__ x4 = (const f4*)x + base4;
    f4* __restrict__       o4 = (f4*)out + base4;

    f4 acc = {0.f, 0.f, 0.f, 0.f};
    #pragma unroll
    for (int kk = 0; kk < 2; ++kk) {
        f4 v[8];
        #pragma unroll
        for (int j = 0; j < 8; ++j) v[j] = x4[t + S * (kk * 8 + j)];
        #pragma unroll
        for (int j = 0; j < 8; ++j) {
            __builtin_nontemporal_store(v[j], &o4[t + S * (kk * 8 + j)]);
            acc += v[j] * v[j];
        }
    }

    __shared__ f4 sm4[4][S4];   // 4.6 KB
    sm4[g][f] = acc;
    __syncthreads();

    const float* sm = (const float*)sm4;
    // thread t owns spatial position t (t < 288 == S)
    part[((size_t)b * NCH + chunk) * S + t] =
        sm[0 * S + t] + sm[1 * S + t] + sm[2 * S + t] + sm[3 * S + t];
}

// ---------------------------------------------------------------------------
// Kernel 2: fused select + zero-patch. Block (chunk, b), 288 threads.
// Each block redundantly reduces its sample's 32x288 partials (36 KB,
// L2/MALL-resident -> ~free, proven in rounds 1-5), ranks rows, compacts
// the RH dropped row indices, then zeroes those rows in its chunk:
// 64 channels x 8 rows x 3 f4 = 1536 NT stores (24 KB/block, 50 MB total).
//
// Tie semantics match stable argsort(ascending)[-RH:]: on equal values the
// larger index wins a top (dropped) slot. cnt (# rows strictly above row t
// in (value,index) order) < RH  <=>  dropped; the ranking is a strict total
// order so dropped rows get unique cnt in [0,RH) -> race-free compaction
// without atomics.
//
// The patch writes are inherently 48 B-granular (that IS the write set);
// lanes 3j..3j+2 write one contiguous 48 B row segment. NT keeps them from
// dirtying cache ahead of the harness fills.
// ---------------------------------------------------------------------------
__global__ __launch_bounds__(288) void k_select_zero(const float* __restrict__ part,
                                                     float* __restrict__ out) {
    const int chunk = blockIdx.x;   // 0..NCH-1
    const int b     = blockIdx.y;
    const int t     = threadIdx.x;  // 0..287

    __shared__ float act[S];
    __shared__ float rm[H];
    __shared__ int   dIdx[RH];

    // 1. reduce the 32 chunk partials -> act[288] (coalesced across t)
    {
        const float* p = part + (size_t)b * NCH * S + t;
        float sum = 0.f;
        #pragma unroll
        for (int ch = 0; ch < NCH; ch++) sum += p[(size_t)ch * S];
        act[t] = sum;
    }
    __syncthreads();

    // 2. per-row max over width -> rm[24]
    if (t < H) {
        float m = act[t * W];
        #pragma unroll
        for (int w = 1; w < W; w++) m = fmaxf(m, act[t * W + w]);
        rm[t] = m;
    }
    __syncthreads();

    // 3. rank rows; compact the top-RH (dropped) row indices
    if (t < H) {
        const float mt = rm[t];
        int cnt = 0;
        #pragma unroll
        for (int j = 0; j < H; j++) {
            float mj = rm[j];
            if (mj > mt || (mj == mt && j > t)) cnt++;
        }
        if (cnt < RH) dIdx[cnt] = t;   // unique slot, no atomics needed
    }
    __syncthreads();

    // 4. zero-patch: 1536 f4 stores over 6 iterations (last one partial)
    f4* __restrict__ o4 = (f4*)out + (size_t)(b * C + chunk * CCH) * S4;
    const f4 z = {0.f, 0.f, 0.f, 0.f};
    #pragma unroll
    for (int k = 0; k < 6; ++k) {
        const int idx = t + 288 * k;           // 0..1727, guard at 1536
        if (idx < CCH * RH * W4) {
            const int c   = idx / (RH * W4);   // channel within chunk
            const int rem = idx - c * (RH * W4);
            const int i   = rem / W4;          // dropped-row slot
            const int j   = rem - i * W4;      // f4 within row
            __builtin_nontemporal_store(z, &o4[c * S4 + dIdx[i] * W4 + j]);
        }
    }
}

extern "C" void kernel_launch(void* const* d_in, const int* in_sizes, int n_in,
                              void* d_out, int out_size, void* d_ws, size_t ws_size,
                              hipStream_t stream) {
    const float* x   = (const float*)d_in[0];
    float*       out = (float*)d_out;

    // ws layout: [ partials: B*NCH*S floats = 2.36 MB ]
    float* part = (float*)d_ws;

    k_energy_copy<<<dim3(NCH, B), 288, 0, stream>>>(x, out, part);
    k_select_zero<<<dim3(NCH, B), 288, 0, stream>>>(part, out);
}

// Round 8
// 277.484 us; speedup vs baseline: 1.1000x; 1.1000x over previous
//
#include <hip/hip_runtime.h>

// Problem constants (static per reference): x shape (B, C, H, W) fp32
#define B   64
#define C   2048
#define H   24
#define W   12
#define S   (H * W)        // 288 spatial positions per (b, c)
#define S4  (S / 4)        // 72 float4 per channel slice
#define W4  (W / 4)        // 3 float4 per row
#define NCH 32             // channel chunks
#define CCH (C / NCH)      // 64 channels per chunk
#define T4  (CCH * S4)     // 4608 float4 per (chunk,b) tile
#define RH  8              // round(0.33 * 24)

// Native clang vector type — required by __builtin_nontemporal_store
// (HIP's float4 is a struct wrapper it rejects). Lowers to dwordx4 ops.
typedef float f4 __attribute__((ext_vector_type(4)));

// ---------------------------------------------------------------------------
// Round-8: revert to the two-pass structure (best measured: 276.2 us).
// Copy-then-patch post-mortem: read-only streaming hits 6.3 TB/s and
// write-only 6.7, but every mixed read+write kernel lands at 2.4-4 TB/s;
// concentrating ALL write traffic into the mixed kernel (copy-then-patch)
// maximizes exposure to that penalty (k_energy_copy: 93 us @ 2.46 TB/s).
// Two-pass keeps the energy pass at read roofline and isolates the mixed
// penalty in one pass. NT stores mandatory (round-6: temporal stores park
// 151 MB dirty in L2/MALL and the writeback drains during the harness
// poison fills, -16% fill BW = +42 us elsewhere; traffic is conserved).
//
// New this round: k_select_copy rebuilt on 256-thread blocks. The old
// 288-thread geometry = 4.5 waves -> rounded to 5, so wave 4 of EVERY block
// ran with 32/64 lanes idle (12.5% of lanes), and 5-wave blocks cap
// residency at 6 blocks/CU = 30/32 waves. 256 threads = 4 full waves,
// 8 blocks/CU = 32/32 waves, and the 2048-block grid is exactly one
// residency generation (no tail).
// ---------------------------------------------------------------------------

// ---------------------------------------------------------------------------
// Kernel 1: read-only energy pass. Block (chunk, b), 288 threads (this one
// keeps the 288-spatial geometry for the LDS reduce; it's at read roofline,
// ~24 us @ 6.3 TB/s, measured round 0). Thread t, iteration k accesses
// float4 index t + 288k -> block walks contiguous 4.6 KB spans, perfectly
// coalesced; thread t's 4 spatial positions fixed -> register accumulate.
// Loads batched 8-deep (compiler alone pipelines only ~4-deep).
// Side effect: x ends up ~half-resident in L3 for kernel 2.
// ---------------------------------------------------------------------------
__global__ __launch_bounds__(288) void k_energy(const float* __restrict__ x,
                                                float* __restrict__ part) {
    const int chunk = blockIdx.x;   // 0..NCH-1
    const int b     = blockIdx.y;   // 0..B-1
    const int t     = threadIdx.x;  // 0..287
    const int f     = t % S4;
    const int g     = t / S4;

    const f4* __restrict__ x4 =
        (const f4*)x + (size_t)(b * C + chunk * CCH) * S4;

    f4 acc = {0.f, 0.f, 0.f, 0.f};
    #pragma unroll
    for (int kk = 0; kk < 2; ++kk) {
        f4 v[8];
        #pragma unroll
        for (int j = 0; j < 8; ++j) v[j] = x4[t + S * (kk * 8 + j)];
        #pragma unroll
        for (int j = 0; j < 8; ++j) acc += v[j] * v[j];
    }

    __shared__ f4 sm4[4][S4];   // 4.6 KB
    sm4[g][f] = acc;
    __syncthreads();

    const float* sm = (const float*)sm4;
    // thread t owns spatial position t (t < 288 == S)
    part[((size_t)b * NCH + chunk) * S + t] =
        sm[0 * S + t] + sm[1 * S + t] + sm[2 * S + t] + sm[3 * S + t];
}

// ---------------------------------------------------------------------------
// Kernel 2 (fused select + masked copy), 256 threads, block (chunk, b).
// Tile = 4608 f4 = 18 f4/thread at stride 256 (perfectly coalesced).
//
// Phases:
//  0. prefetch first 8 f4 (mask-independent) -> mask phase hides under
//     x-load latency instead of being a serial prologue.
//  1. reduce 32 chunk partials -> act[288] (36 KB L2/L3-resident, ~free,
//     proven rounds 1-7). 256 threads cover 288 positions in 2 strides.
//  2. per-row max, 3. rank rows (code byte-identical to all passing rounds;
//     tie semantics = stable argsort(ascending)[-RH:], larger index wins a
//     drop slot on equal values).
//  4. masked copy: multiply form, branch-free (round-1 lesson: the
//     divergent-branch form breaks write-combining -> partial-line
//     overshoot). h varies per element here (idx%72/3) -> per-element LDS
//     mask read (cheap; VALUBusy has been <3% throughout). keep is 1.0/0.0;
//     0*x==0 exactly (finite inputs), 1*x bit-exact. NT stores.
// ---------------------------------------------------------------------------
__global__ __launch_bounds__(256) void k_select_copy(const float* __restrict__ x,
                                                     const float* __restrict__ part,
                                                     float* __restrict__ out) {
    const int chunk = blockIdx.x;   // 0..NCH-1
    const int b     = blockIdx.y;
    const int t     = threadIdx.x;  // 0..255

    __shared__ float act[S];
    __shared__ float rm[H];
    __shared__ float keepRow[H];

    const size_t base4 = (size_t)(b * C + chunk * CCH) * S4;
    const f4* __restrict__ x4 = (const f4*)x + base4;
    f4* __restrict__       o4 = (f4*)out + base4;

    // 0. prefetch first 8 f4 per thread (loads are mask-independent)
    f4 v[8];
    #pragma unroll
    for (int j = 0; j < 8; ++j) v[j] = x4[t + 256 * j];

    // 1. reduce the 32 chunk partials -> act[288]
    for (int i = t; i < S; i += 256) {
        const float* p = part + (size_t)b * NCH * S + i;
        float sum = 0.f;
        #pragma unroll
        for (int ch = 0; ch < NCH; ch++) sum += p[(size_t)ch * S];
        act[i] = sum;
    }
    __syncthreads();

    // 2. per-row max over width -> rm[24]
    if (t < H) {
        float m = act[t * W];
        #pragma unroll
        for (int w = 1; w < W; w++) m = fmaxf(m, act[t * W + w]);
        rm[t] = m;
    }
    __syncthreads();

    // 3. rank rows; drop the top RH (ties: larger index dropped first)
    if (t < H) {
        const float mt = rm[t];
        int cnt = 0;
        #pragma unroll
        for (int j = 0; j < H; j++) {
            float mj = rm[j];
            if (mj > mt || (mj == mt && j > t)) cnt++;
        }
        keepRow[t] = (cnt < RH) ? 0.0f : 1.0f;
    }
    __syncthreads();

    // 4. masked copy: 18 f4/thread = 8 (prefetched) + 8 + 2
    #pragma unroll
    for (int j = 0; j < 8; ++j) {
        const int idx = t + 256 * j;
        const int h   = (idx % S4) / W4;
        __builtin_nontemporal_store(v[j] * keepRow[h], &o4[idx]);
    }

    #pragma unroll
    for (int j = 0; j < 8; ++j) v[j] = x4[t + 256 * (8 + j)];
    #pragma unroll
    for (int j = 0; j < 8; ++j) {
        const int idx = t + 256 * (8 + j);
        const int h   = (idx % S4) / W4;
        __builtin_nontemporal_store(v[j] * keepRow[h], &o4[idx]);
    }

    #pragma unroll
    for (int j = 0; j < 2; ++j) v[j] = x4[t + 256 * (16 + j)];
    #pragma unroll
    for (int j = 0; j < 2; ++j) {
        const int idx = t + 256 * (16 + j);
        const int h   = (idx % S4) / W4;
        __builtin_nontemporal_store(v[j] * keepRow[h], &o4[idx]);
    }
}

extern "C" void kernel_launch(void* const* d_in, const int* in_sizes, int n_in,
                              void* d_out, int out_size, void* d_ws, size_t ws_size,
                              hipStream_t stream) {
    const float* x   = (const float*)d_in[0];
    float*       out = (float*)d_out;

    // ws layout: [ partials: B*NCH*S floats = 2.36 MB ]
    float* part = (float*)d_ws;

    k_energy<<<dim3(NCH, B), 288, 0, stream>>>(x, part);
    k_select_copy<<<dim3(NCH, B), 256, 0, stream>>>(x, part, out);
}

// Round 9
// 276.689 us; speedup vs baseline: 1.1032x; 1.0029x over previous
//
#include <hip/hip_runtime.h>

// Problem constants (static per reference): x shape (B, C, H, W) fp32
#define B   64
#define C   2048
#define H   24
#define W   12
#define S   (H * W)        // 288 spatial positions per (b, c)
#define S4  (S / 4)        // 72 float4 per channel slice
#define W4  (W / 4)        // 3 float4 per row
#define NCH 32             // channel chunks
#define CCH (C / NCH)      // 64 channels per chunk
#define RH  8              // round(0.33 * 24)

// Native clang vector type — required by __builtin_nontemporal_store
// (HIP's float4 is a struct wrapper it rejects). Lowers to dwordx4 ops.
typedef float f4 __attribute__((ext_vector_type(4)));

// ---------------------------------------------------------------------------
// Round-9: two-pass structure (best measured band 276-278 us) + LOAD-ONLY
// masking in the copy pass.
// Round-1 lesson refined: branching around loads AND stores broke
// write-combining (partial-wave stores, +24 MB write overshoot, -30 us).
// This version keeps every store unconditional/full-wave (contiguous 1 KB
// per wave instruction) and masks ONLY the loads: v is zero-initialized,
// kept lanes overwrite it with the exec-masked load batch. Dropped lanes
// (1/3 of rows) issue no fetch -> saves ~25-30% of k2's read service
// (48 B dropped row segments span 1.5-2 32 B sectors).
// NT stores mandatory (round-6: temporal stores park 151 MB dirty in
// L2/MALL; writeback drains during the harness poison fills at -16% fill
// BW; traffic is conserved, NT keeps it inside our own kernel).
// ---------------------------------------------------------------------------

// ---------------------------------------------------------------------------
// Kernel 1: read-only energy pass. Block (chunk, b), 288 threads.
// Thread t, iteration k accesses float4 index t + 288k within the chunk's
// 4608-float4 span -> the block walks contiguous 4.6 KB spans, perfectly
// coalesced. Thread t's 4 spatial positions are fixed -> register
// accumulate. Loads batched 8-deep. Measured at read roofline (~24 us).
// ---------------------------------------------------------------------------
__global__ __launch_bounds__(288) void k_energy(const float* __restrict__ x,
                                                float* __restrict__ part) {
    const int chunk = blockIdx.x;   // 0..NCH-1
    const int b     = blockIdx.y;   // 0..B-1
    const int t     = threadIdx.x;  // 0..287
    const int f     = t % S4;
    const int g     = t / S4;

    const f4* __restrict__ x4 =
        (const f4*)x + (size_t)(b * C + chunk * CCH) * S4;

    f4 acc = {0.f, 0.f, 0.f, 0.f};
    #pragma unroll
    for (int kk = 0; kk < 2; ++kk) {
        f4 v[8];
        #pragma unroll
        for (int j = 0; j < 8; ++j) v[j] = x4[t + S * (kk * 8 + j)];
        #pragma unroll
        for (int j = 0; j < 8; ++j) acc += v[j] * v[j];
    }

    __shared__ f4 sm4[4][S4];   // 4.6 KB
    sm4[g][f] = acc;
    __syncthreads();

    const float* sm = (const float*)sm4;
    // thread t owns spatial position t (t < 288 == S)
    part[((size_t)b * NCH + chunk) * S + t] =
        sm[0 * S + t] + sm[1 * S + t] + sm[2 * S + t] + sm[3 * S + t];
}

// ---------------------------------------------------------------------------
// Kernel 2 (fused select + masked copy), 288 threads, block (chunk, b).
// Since idx = t + 288k and 288 % 72 == 0, the spatial row h = (t%72)/3 is
// CONSTANT per thread -> keep is loop-invariant; one LDS read.
//
// Phases:
//  1. reduce 32 chunk partials -> act[288] (36 KB L2/L3-resident, ~free,
//     proven across rounds 1-8).
//  2. per-row max, 3. rank rows (code byte-identical to all passing rounds;
//     tie semantics = stable argsort(ascending)[-RH:], larger index wins a
//     drop slot on equal values).
//  4. copy: v zero-init; ONLY the loads sit inside if(keep) (exec-masked,
//     dropped lanes fetch nothing); stores unconditional full-wave NT ->
//     write-combining intact. v==0.0 exactly for dropped lanes; kept lanes
//     are bit-exact copies.
// ---------------------------------------------------------------------------
__global__ __launch_bounds__(288) void k_select_copy(const float* __restrict__ x,
                                                     const float* __restrict__ part,
                                                     float* __restrict__ out) {
    const int chunk = blockIdx.x;   // 0..NCH-1
    const int b     = blockIdx.y;
    const int t     = threadIdx.x;  // 0..287

    __shared__ float act[S];
    __shared__ float rm[H];
    __shared__ int   keepRow[H];

    // 1. reduce the 32 chunk partials -> act[288] (coalesced across t)
    {
        const float* p = part + (size_t)b * NCH * S + t;
        float sum = 0.f;
        #pragma unroll
        for (int ch = 0; ch < NCH; ch++) sum += p[(size_t)ch * S];
        act[t] = sum;
    }
    __syncthreads();

    // 2. per-row max over width -> rm[24]
    if (t < H) {
        float m = act[t * W];
        #pragma unroll
        for (int w = 1; w < W; w++) m = fmaxf(m, act[t * W + w]);
        rm[t] = m;
    }
    __syncthreads();

    // 3. rank rows; drop the top RH (ties: larger index dropped first)
    if (t < H) {
        const float mt = rm[t];
        int cnt = 0;
        #pragma unroll
        for (int j = 0; j < H; j++) {
            float mj = rm[j];
            if (mj > mt || (mj == mt && j > t)) cnt++;
        }
        keepRow[t] = (cnt < RH) ? 0 : 1;
    }
    __syncthreads();

    // 4. copy: masked loads, unconditional full-wave stores
    const int h    = (t % S4) / W4;
    const int keep = keepRow[h];

    const size_t base4 = (size_t)(b * C + chunk * CCH) * S4;
    const f4* __restrict__ x4 = (const f4*)x + base4;
    f4* __restrict__       o4 = (f4*)out + base4;

    #pragma unroll
    for (int kk = 0; kk < 2; ++kk) {
        f4 v[8];
        #pragma unroll
        for (int j = 0; j < 8; ++j) v[j] = (f4){0.f, 0.f, 0.f, 0.f};
        if (keep) {
            #pragma unroll
            for (int j = 0; j < 8; ++j) v[j] = x4[t + S * (kk * 8 + j)];
        }
        #pragma unroll
        for (int j = 0; j < 8; ++j)
            __builtin_nontemporal_store(v[j], &o4[t + S * (kk * 8 + j)]);
    }
}

extern "C" void kernel_launch(void* const* d_in, const int* in_sizes, int n_in,
                              void* d_out, int out_size, void* d_ws, size_t ws_size,
                              hipStream_t stream) {
    const float* x   = (const float*)d_in[0];
    float*       out = (float*)d_out;

    // ws layout: [ partials: B*NCH*S floats = 2.36 MB ]
    float* part = (float*)d_ws;

    k_energy<<<dim3(NCH, B), 288, 0, stream>>>(x, part);
    k_select_copy<<<dim3(NCH, B), 288, 0, stream>>>(x, part, out);
}